// Round 9
// baseline (43.875 us; speedup 1.0000x reference)
//
#include <hip/hip_runtime.h>
#include <math.h>

#define SEQ   4096
#define HD    64
#define NH    16
#define WHALF 256
#define QB    128    // queries per block; 8 waves: 4 q-pair groups x 2 chunk owners
#define KT    64     // key tile staged in LDS
#define KSTR  72     // stride (shorts) for LDS planes: 144B rows -> b128 R/W at 8-phase bank floor
#define PLANE (KT * KSTR)

typedef __attribute__((ext_vector_type(8))) __bf16 bf16x8;
typedef __attribute__((ext_vector_type(8))) short short8v;
typedef __attribute__((ext_vector_type(4))) float f32x4;

__device__ __forceinline__ short bf16bits(float x) {
    __bf16 b = (__bf16)x;            // RTN
    return __builtin_bit_cast(short, b);
}

#define MFMA32(A, B, C) __builtin_amdgcn_mfma_f32_16x16x32_bf16((A), (B), (C), 0, 0, 0)

#if __has_builtin(__builtin_amdgcn_exp2f)
#define EXP2F(x) __builtin_amdgcn_exp2f(x)
#else
#define EXP2F(x) __exp2f(x)
#endif

__global__ __launch_bounds__(512, 4)
void swa_mfma9_kernel(const float* __restrict__ q,
                      const float* __restrict__ k,
                      const float* __restrict__ v,
                      float* __restrict__ out) {
    // double-buffered: [buf][plane] planes: 0=K 1=V(transposed) ; 36864 B
    // (reused as f32 combine scratch after the main loop)
    __shared__ short smem[2 * 2 * PLANE];

    // ---- XCD-aware bijective swizzle: 512 blocks = 8 XCDs x 64; head-major chunks ----
    const int orig = blockIdx.x;
    const int work = ((orig & 7) << 6) + (orig >> 3);
    const int h    = work >> 5;
    const int q0   = (work & 31) * QB;

    const int t    = threadIdx.x;
    const int lane = t & 63;
    const int w    = t >> 6;             // wave 0..7
    const int n15  = lane & 15;
    const int g    = lane >> 4;          // 0..3

    const int wq   = w & 3;              // q-pair group: queries [qa, qa+32)
    const int wk   = w >> 2;             // chunk owner: chunk kc=wk of every tile
    const int qa     = q0 + wq * 32;
    const int qrow_a = qa + n15;
    const int qrow_b = qa + 16 + n15;

    // scores in log2 domain (fold 1/sqrt(64)*log2(e) into Q); NO max-shift:
    // softmax is shift-invariant, scores are O(10) in log2 domain, and the
    // shift-free form makes split-key partials combine by EXACT addition.
    const float SCALE = 0.125f * 1.44269504088896340736f;

    // ---- Q fragments for both q-tiles, pre-scaled, plain bf16 ----
    bf16x8 qfa[2], qfb[2];
    {
        const float* qpa = q + ((size_t)h * SEQ + qrow_a) * HD;
        const float* qpb = q + ((size_t)h * SEQ + qrow_b) * HD;
        #pragma unroll
        for (int c = 0; c < 2; ++c) {
            const float4* pa4 = reinterpret_cast<const float4*>(qpa + 32 * c + 8 * g);
            const float4* pb4 = reinterpret_cast<const float4*>(qpb + 32 * c + 8 * g);
            float4 a0 = pa4[0], a1 = pa4[1], b0 = pb4[0], b1 = pb4[1];
            float xa[8] = {a0.x, a0.y, a0.z, a0.w, a1.x, a1.y, a1.z, a1.w};
            float xb[8] = {b0.x, b0.y, b0.z, b0.w, b1.x, b1.y, b1.z, b1.w};
            short8v qa8, qb8;
            #pragma unroll
            for (int j = 0; j < 8; ++j) {
                qa8[j] = bf16bits(xa[j] * SCALE);
                qb8[j] = bf16bits(xb[j] * SCALE);
            }
            qfa[c] = __builtin_bit_cast(bf16x8, qa8);
            qfb[c] = __builtin_bit_cast(bf16x8, qb8);
        }
    }

    // ones A-fragment for the lsum MFMA (row 0 of A = ones): register constant
    bf16x8 ones8;
    {
        short8v o8;
        const short ov = (n15 == 0) ? (short)0x3F80 : (short)0;
        #pragma unroll
        for (int j = 0; j < 8; ++j) o8[j] = ov;
        ones8 = __builtin_bit_cast(bf16x8, o8);
    }

    f32x4 accOa[4], accOb[4];
    #pragma unroll
    for (int dt = 0; dt < 4; ++dt) {
        accOa[dt] = (f32x4){0.f, 0.f, 0.f, 0.f};
        accOb[dt] = (f32x4){0.f, 0.f, 0.f, 0.f};
    }
    f32x4 accLa = (f32x4){0.f, 0.f, 0.f, 0.f};
    f32x4 accLb = (f32x4){0.f, 0.f, 0.f, 0.f};

    int k0 = q0 - WHALF;           if (k0 < 0) k0 = 0;
    int k1 = q0 + QB - 1 + WHALF;  if (k1 > SEQ - 1) k1 = SEQ - 1;
    const int nt = (k1 + 1 - k0) >> 6;   // always whole tiles

    const float4* kb4 = reinterpret_cast<const float4*>(k + ((size_t)h * SEQ) * HD);
    const float*  vp  = v + ((size_t)h * SEQ) * HD;

    // ---- 2-tile-deep register prefetch ----
    float4 kreg[2];
    float  vreg[8];

    #define LOADT(KTV)                                                       \
        {                                                                    \
            const int kt_ = (KTV);                                           \
            kreg[0] = kb4[(size_t)kt_ * 16 + t * 2 + 0];                     \
            kreg[1] = kb4[(size_t)kt_ * 16 + t * 2 + 1];                     \
            _Pragma("unroll")                                                \
            for (int j = 0; j < 8; ++j)                                      \
                vreg[j] = vp[(size_t)(kt_ + 8 * w + j) * HD + lane];         \
        }

    // ---- stage regs -> buffer b (identical mapping to validated R7 code) ----
    auto STAGE = [&](int b) {
        short* Kb = smem + b * 2 * PLANE;
        short* Vb = Kb + PLANE;

        const int p  = t >> 3;           // physical key row in tile (0..63)
        const int q5 = p & 31;
        const int R  = (p & 32) + (((q5 >> 2) & 1) << 4) + ((q5 >> 3) << 2) + (q5 & 3);

        const float* kf = reinterpret_cast<const float*>(&kreg[0]);
        short8v k8;
        #pragma unroll
        for (int j = 0; j < 8; ++j) k8[j] = bf16bits(kf[j]);
        *reinterpret_cast<short8v*>(&Kb[R * KSTR + (t & 7) * 8]) = k8;

        short8v v8;
        #pragma unroll
        for (int j = 0; j < 8; ++j) v8[j] = bf16bits(vreg[j]);
        *reinterpret_cast<short8v*>(&Vb[lane * KSTR + 8 * w]) = v8;   // [d=lane][key 8w..8w+7]
    };

    LOADT(k0);
    STAGE(0);
    if (nt > 1) LOADT(k0 + KT);
    __syncthreads();

    for (int i = 0; i < nt; ++i) {
        const int kt  = k0 + i * KT;
        const int cur = i & 1;

        if (i + 1 < nt) {
            STAGE(cur ^ 1);
            if (i + 2 < nt) LOADT(k0 + (i + 2) * KT);
        }

        const short* Kb = smem + cur * 2 * PLANE;
        const short* Vb = Kb + PLANE;

        // this wave's single chunk of the tile
        const int cb = kt + wk * 32;
        const bool aact = !(cb > qa + 15 + WHALF || cb + 31 < qa - WHALF);
        const bool bact = !(cb > qa + 31 + WHALF || cb + 31 < qa + 16 - WHALF);

        if (aact || bact) {
            // ---- S^T = K·Q^T for both q-tiles; K fragments read ONCE ----
            f32x4 Sa[2], Sb[2];
            __builtin_amdgcn_s_setprio(1);
            #pragma unroll
            for (int s = 0; s < 2; ++s) {
                const int krow = (wk * 32 + s * 16 + n15) * KSTR + 8 * g;
                bf16x8 k0f = __builtin_bit_cast(bf16x8, *reinterpret_cast<const short8v*>(&Kb[krow]));
                bf16x8 k1f = __builtin_bit_cast(bf16x8, *reinterpret_cast<const short8v*>(&Kb[krow + 32]));
                if (aact) {
                    f32x4 a = (f32x4){0.f, 0.f, 0.f, 0.f};
                    a = MFMA32(k0f, qfa[0], a);
                    a = MFMA32(k1f, qfa[1], a);
                    Sa[s] = a;
                }
                if (bact) {
                    f32x4 b = (f32x4){0.f, 0.f, 0.f, 0.f};
                    b = MFMA32(k0f, qfb[0], b);
                    b = MFMA32(k1f, qfb[1], b);
                    Sb[s] = b;
                }
            }
            __builtin_amdgcn_s_setprio(0);

            // ---- P = exp2(scores) per tile (lane's keys: cb+8g .. cb+8g+7) ----
            const int kbase = cb + 8 * g;
            bf16x8 pa8, pb8;
            if (aact) {
                short8v p8s;
                const bool interior = (cb >= qa + 15 - WHALF) && (cb + 31 <= qa + WHALF);
                if (interior) {
                    #pragma unroll
                    for (int j = 0; j < 8; ++j)
                        p8s[j] = bf16bits(EXP2F(Sa[j >> 2][j & 3]));
                } else {
                    #pragma unroll
                    for (int j = 0; j < 8; ++j) {
                        int key = kbase + j;
                        bool valid = (key >= qrow_a - WHALF) && (key <= qrow_a + WHALF);
                        p8s[j] = bf16bits(EXP2F(valid ? Sa[j >> 2][j & 3] : -1e30f));
                    }
                }
                pa8 = __builtin_bit_cast(bf16x8, p8s);
            }
            if (bact) {
                short8v p8s;
                const bool interior = (cb >= qa + 31 - WHALF) && (cb + 31 <= qa + 16 + WHALF);
                if (interior) {
                    #pragma unroll
                    for (int j = 0; j < 8; ++j)
                        p8s[j] = bf16bits(EXP2F(Sb[j >> 2][j & 3]));
                } else {
                    #pragma unroll
                    for (int j = 0; j < 8; ++j) {
                        int key = kbase + j;
                        bool valid = (key >= qrow_b - WHALF) && (key <= qrow_b + WHALF);
                        p8s[j] = bf16bits(EXP2F(valid ? Sb[j >> 2][j & 3] : -1e30f));
                    }
                }
                pb8 = __builtin_bit_cast(bf16x8, p8s);
            }

            // ---- PV for both tiles; V fragments read ONCE; + ones-MFMA lsum ----
            __builtin_amdgcn_s_setprio(1);
            #pragma unroll
            for (int dt = 0; dt < 4; ++dt) {
                const int vrow = (dt * 16 + n15) * KSTR + wk * 32 + 8 * g;
                bf16x8 vf = __builtin_bit_cast(bf16x8, *reinterpret_cast<const short8v*>(&Vb[vrow]));
                if (aact) accOa[dt] = MFMA32(vf, pa8, accOa[dt]);
                if (bact) accOb[dt] = MFMA32(vf, pb8, accOb[dt]);
            }
            if (aact) accLa = MFMA32(ones8, pa8, accLa);
            if (bact) accLb = MFMA32(ones8, pb8, accLb);
            __builtin_amdgcn_s_setprio(0);
        }

        if (i + 1 < nt) __syncthreads();
    }

    // ---- combine: waves w and w+4 hold disjoint-key partials for the same
    // queries; shift-free softmax => exact addition. Reuse smem as scratch. ----
    __syncthreads();
    float* scratch = reinterpret_cast<float*>(smem);
    if (w >= 4) {
        const int base = ((w - 4) * 64 + lane) * 36;   // 36 f32 stride: 144B, 16B-aligned
        #pragma unroll
        for (int dt = 0; dt < 4; ++dt) {
            *reinterpret_cast<f32x4*>(&scratch[base + dt * 4])      = accOa[dt];
            *reinterpret_cast<f32x4*>(&scratch[base + 16 + dt * 4]) = accOb[dt];
        }
        scratch[base + 32] = accLa[0];
        scratch[base + 33] = accLb[0];
    }
    __syncthreads();
    if (w < 4) {
        const int base = (w * 64 + lane) * 36;
        #pragma unroll
        for (int dt = 0; dt < 4; ++dt) {
            accOa[dt] += *reinterpret_cast<const f32x4*>(&scratch[base + dt * 4]);
            accOb[dt] += *reinterpret_cast<const f32x4*>(&scratch[base + 16 + dt * 4]);
        }
        accLa[0] += scratch[base + 32];
        accLb[0] += scratch[base + 33];

        // lsum sits in accL*[0] of g=0 lanes; broadcast per query column
        const float lsa = __shfl(accLa[0], n15);
        const float lsb = __shfl(accLb[0], n15);
        const float inva = 1.0f / lsa;
        const float invb = 1.0f / lsb;
        float* opa = out + ((size_t)h * SEQ + qrow_a) * HD;
        float* opb = out + ((size_t)h * SEQ + qrow_b) * HD;
        #pragma unroll
        for (int dt = 0; dt < 4; ++dt) {
            *reinterpret_cast<f32x4*>(opa + dt * 16 + 4 * g) = accOa[dt] * inva;
            *reinterpret_cast<f32x4*>(opb + dt * 16 + 4 * g) = accOb[dt] * invb;
        }
    }
}

extern "C" void kernel_launch(void* const* d_in, const int* in_sizes, int n_in,
                              void* d_out, int out_size, void* d_ws, size_t ws_size,
                              hipStream_t stream) {
    const float* q = (const float*)d_in[0];
    const float* k = (const float*)d_in[1];
    const float* v = (const float*)d_in[2];
    float* out = (float*)d_out;

    dim3 grid(NH * (SEQ / QB));   // 512 blocks (1D for swizzle)
    dim3 block(512);              // 8 waves
    hipLaunchKernelGGL(swa_mfma9_kernel, grid, block, 0, stream, q, k, v, out);
}

// Round 10
// 27.344 us; speedup vs baseline: 1.6046x; 1.6046x over previous
//
#include <hip/hip_runtime.h>
#include <math.h>

#define SEQ   4096
#define HD    64
#define NH    16
#define WHALF 256
#define QB    128    // queries per block = 8 waves x 16
#define KT    128    // keys staged per barrier (2 former tiles)
#define KSTR  72     // K plane d-stride (shorts): 144B rows -> b128 R/W at 8-phase bank floor
#define VSTR  136    // V plane key-stride (shorts): 272B rows -> b128 R/W at 8-phase bank floor
#define KPLANE (KT * KSTR)   // 9216 shorts
#define VPLANE (HD * VSTR)   // 8704 shorts
#define BUFSZ  (KPLANE + VPLANE)

typedef __attribute__((ext_vector_type(8))) __bf16 bf16x8;
typedef __attribute__((ext_vector_type(8))) short short8v;
typedef __attribute__((ext_vector_type(4))) float f32x4;

__device__ __forceinline__ short bf16bits(float x) {
    __bf16 b = (__bf16)x;            // RTN
    return __builtin_bit_cast(short, b);
}

#define MFMA32(A, B, C) __builtin_amdgcn_mfma_f32_16x16x32_bf16((A), (B), (C), 0, 0, 0)

#if __has_builtin(__builtin_amdgcn_exp2f)
#define EXP2F(x) __builtin_amdgcn_exp2f(x)
#else
#define EXP2F(x) __exp2f(x)
#endif

__global__ __launch_bounds__(512, 4)
void swa_mfma10_kernel(const float* __restrict__ q,
                       const float* __restrict__ k,
                       const float* __restrict__ v,
                       float* __restrict__ out) {
    // double-buffered: [buf][K plane | V plane] ; 71680 B total -> 2 blocks/CU
    __shared__ short smem[2 * BUFSZ];

    // ---- XCD-aware bijective swizzle: 512 blocks = 8 XCDs x 64; head-major chunks ----
    const int orig = blockIdx.x;
    const int work = ((orig & 7) << 6) + (orig >> 3);
    const int h    = work >> 5;
    const int q0   = (work & 31) * QB;

    const int t    = threadIdx.x;
    const int lane = t & 63;
    const int w    = t >> 6;             // wave 0..7
    const int n15  = lane & 15;
    const int g    = lane >> 4;          // 0..3
    const int qrow = q0 + w * 16 + n15;  // this lane's query

    // scores in log2 domain (fold 1/sqrt(64)*log2(e) into Q); NO max-shift:
    // softmax is shift-invariant and scores are O(10) in the log2 domain.
    const float SCALE = 0.125f * 1.44269504088896340736f;

    // ---- Q fragments (B-operand of S^T = K·Q^T), pre-scaled, plain bf16 ----
    bf16x8 qf[2];
    {
        const float* qp = q + ((size_t)h * SEQ + qrow) * HD;
        #pragma unroll
        for (int c = 0; c < 2; ++c) {
            const float4* p4 = reinterpret_cast<const float4*>(qp + 32 * c + 8 * g);
            float4 a = p4[0], b = p4[1];
            float xs[8] = {a.x, a.y, a.z, a.w, b.x, b.y, b.z, b.w};
            short8v q8;
            #pragma unroll
            for (int j = 0; j < 8; ++j) q8[j] = bf16bits(xs[j] * SCALE);
            qf[c] = __builtin_bit_cast(bf16x8, q8);
        }
    }

    // ones A-fragment for the lsum MFMA (row 0 of A = ones): register constant
    bf16x8 ones8;
    {
        short8v o8;
        const short ov = (n15 == 0) ? (short)0x3F80 : (short)0;
        #pragma unroll
        for (int j = 0; j < 8; ++j) o8[j] = ov;
        ones8 = __builtin_bit_cast(bf16x8, o8);
    }

    f32x4 accO[4];
    #pragma unroll
    for (int dt = 0; dt < 4; ++dt) accO[dt] = (f32x4){0.f, 0.f, 0.f, 0.f};
    f32x4 accL = (f32x4){0.f, 0.f, 0.f, 0.f};   // lsum lands in reg 0 of g=0 lanes

    int k0 = q0 - WHALF;           if (k0 < 0) k0 = 0;
    int k1 = q0 + QB - 1 + WHALF;  if (k1 > SEQ - 1) k1 = SEQ - 1;
    const int nt = (k1 + 1 - k0) >> 7;   // window is always a multiple of 128

    const int wqmin = q0 + w * 16;
    const int wqmax = wqmin + 15;
    const int wlo   = wqmin - WHALF;   // wave union window
    const int whi   = wqmax + WHALF;

    const float4* kb4 = reinterpret_cast<const float4*>(k + ((size_t)h * SEQ) * HD);
    const float*  vp  = v + ((size_t)h * SEQ) * HD;

    // ---- 2-buffer-deep register prefetch (256 keys ahead) ----
    float4 kreg[4];
    float  vreg[16];

    #define LOADT(KTV)                                                        \
        {                                                                     \
            const int kt_ = (KTV);                                            \
            _Pragma("unroll")                                                 \
            for (int i = 0; i < 4; ++i)                                       \
                kreg[i] = kb4[(size_t)kt_ * 16 + t * 4 + i];                  \
            _Pragma("unroll")                                                 \
            for (int j = 0; j < 16; ++j)                                      \
                vreg[j] = vp[(size_t)(kt_ + 16 * w + j) * HD + lane];         \
        }

    // ---- stage regs -> buffer b.  K rows PERMUTED (within each 32-key chunk)
    // so the QK D-fragment hands each lane keys 8g..8g+7 (K=32 PV B-order):
    // physical key p: R = (p & 96) | perm5(p & 31), perm5 validated in R7.
    auto STAGE = [&](int b) {
        short* Kb = smem + b * BUFSZ;
        short* Vb = Kb + KPLANE;

        const int p  = t >> 2;           // physical key row (0..127); 4 threads/row
        const int q5 = p & 31;
        const int R  = (p & 96) + (((q5 >> 2) & 1) << 4) + ((q5 >> 3) << 2) + (q5 & 3);

        const float* kf = reinterpret_cast<const float*>(&kreg[0]);
        short8v k8a, k8b;
        #pragma unroll
        for (int j = 0; j < 8; ++j) {
            k8a[j] = bf16bits(kf[j]);
            k8b[j] = bf16bits(kf[8 + j]);
        }
        *reinterpret_cast<short8v*>(&Kb[R * KSTR + (t & 3) * 16])     = k8a;
        *reinterpret_cast<short8v*>(&Kb[R * KSTR + (t & 3) * 16 + 8]) = k8b;

        short8v v8a, v8b;
        #pragma unroll
        for (int j = 0; j < 8; ++j) {
            v8a[j] = bf16bits(vreg[j]);
            v8b[j] = bf16bits(vreg[8 + j]);
        }
        *reinterpret_cast<short8v*>(&Vb[lane * VSTR + 16 * w])     = v8a;  // [d=lane][key 16w..]
        *reinterpret_cast<short8v*>(&Vb[lane * VSTR + 16 * w + 8]) = v8b;
    };

    LOADT(k0);
    STAGE(0);
    if (nt > 1) LOADT(k0 + KT);
    __syncthreads();

    for (int i = 0; i < nt; ++i) {
        const int kt  = k0 + i * KT;
        const int cur = i & 1;

        if (i + 1 < nt) {
            STAGE(cur ^ 1);
            if (i + 2 < nt) LOADT(k0 + (i + 2) * KT);
        }

        const short* Kb = smem + cur * BUFSZ;
        const short* Vb = Kb + KPLANE;

        #pragma unroll
        for (int kc = 0; kc < 4; ++kc) {
            const int cb = kt + kc * 32;
            if (cb > whi || cb + 31 < wlo) continue;   // wave-uniform chunk skip

            // ---- S^T = K·Q^T (two chained 16x16x32 per 16-key half) ----
            f32x4 S[2];
            __builtin_amdgcn_s_setprio(1);
            #pragma unroll
            for (int s = 0; s < 2; ++s) {
                const int krow = (kc * 32 + s * 16 + n15) * KSTR + 8 * g;
                bf16x8 k0f = __builtin_bit_cast(bf16x8, *reinterpret_cast<const short8v*>(&Kb[krow]));
                bf16x8 k1f = __builtin_bit_cast(bf16x8, *reinterpret_cast<const short8v*>(&Kb[krow + 32]));
                f32x4 a = (f32x4){0.f, 0.f, 0.f, 0.f};
                a = MFMA32(k0f, qf[0], a);
                a = MFMA32(k1f, qf[1], a);
                S[s] = a;
            }
            __builtin_amdgcn_s_setprio(0);

            // lane's 8 scores are keys cb+8g .. cb+8g+7:  sc[j] = S[j>>2][j&3]
            // P = exp2(sc) directly (no shift); masked -> exp2(-1e30) == 0
            short8v p8s;
            const bool interior = (cb >= wqmax - WHALF) && (cb + 31 <= wqmin + WHALF);
            if (interior) {
                #pragma unroll
                for (int j = 0; j < 8; ++j)
                    p8s[j] = bf16bits(EXP2F(S[j >> 2][j & 3]));
            } else {
                const int kbase = cb + 8 * g;
                #pragma unroll
                for (int j = 0; j < 8; ++j) {
                    int key = kbase + j;
                    bool valid = (key >= qrow - WHALF) && (key <= qrow + WHALF);
                    p8s[j] = bf16bits(EXP2F(valid ? S[j >> 2][j & 3] : -1e30f));
                }
            }
            bf16x8 p8 = __builtin_bit_cast(bf16x8, p8s);

            // ---- PV: O^T += V^T · P^T via 16x16x32, + register-ones lsum MFMA ----
            __builtin_amdgcn_s_setprio(1);
            #pragma unroll
            for (int dt = 0; dt < 4; ++dt) {
                const int vrow = (dt * 16 + n15) * VSTR + kc * 32 + 8 * g;
                bf16x8 vf = __builtin_bit_cast(bf16x8, *reinterpret_cast<const short8v*>(&Vb[vrow]));
                accO[dt] = MFMA32(vf, p8, accO[dt]);
            }
            accL = MFMA32(ones8, p8, accL);   // row 0 = sum_k p[k] for query n15
            __builtin_amdgcn_s_setprio(0);
        }

        if (i + 1 < nt) __syncthreads();   // next buffer staged by all waves
    }

    // ---- epilogue: lsum sits in accL[0] of the g=0 lane for each query ----
    const float lsum = __shfl(accL[0], n15);   // broadcast from lane id n15 (g=0 block)
    const float inv  = 1.0f / lsum;
    float* op = out + ((size_t)h * SEQ + qrow) * HD;
    #pragma unroll
    for (int dt = 0; dt < 4; ++dt) {
        *reinterpret_cast<f32x4*>(op + dt * 16 + 4 * g) = accO[dt] * inv;
    }
}

extern "C" void kernel_launch(void* const* d_in, const int* in_sizes, int n_in,
                              void* d_out, int out_size, void* d_ws, size_t ws_size,
                              hipStream_t stream) {
    const float* q = (const float*)d_in[0];
    const float* k = (const float*)d_in[1];
    const float* v = (const float*)d_in[2];
    float* out = (float*)d_out;

    dim3 grid(NH * (SEQ / QB));   // 512 blocks (1D for swizzle)
    dim3 block(512);              // 8 waves
    hipLaunchKernelGGL(swa_mfma10_kernel, grid, block, 0, stream, q, k, v, out);
}